// Round 3
// baseline (219.296 us; speedup 1.0000x reference)
//
#include <hip/hip_runtime.h>

#define DD 128

typedef float vf4 __attribute__((ext_vector_type(4)));

// quad_perm DPP ctrl: [1,0,3,2] = 0xB1 (xor 1), [2,3,0,1] = 0x4E (xor 2)
__device__ __forceinline__ vf4 process_row(vf4 v, int lane_r) {
    int dbase = lane_r * 4;
    // local argmax over this lane's 4 elements (first-occurrence)
    float m = v.x; int mi = dbase;
    if (v.y > m) { m = v.y; mi = dbase + 1; }
    if (v.z > m) { m = v.z; mi = dbase + 2; }
    if (v.w > m) { m = v.w; mi = dbase + 3; }

    // quad (4-lane) argmax butterfly via DPP — VALU speed, no DS ops
    {
        float om = __int_as_float(__builtin_amdgcn_mov_dpp(__float_as_int(m), 0xB1, 0xF, 0xF, true));
        int   oi = __builtin_amdgcn_mov_dpp(mi, 0xB1, 0xF, 0xF, true);
        if (om > m || (om == m && oi < mi)) { m = om; mi = oi; }
    }
    {
        float om = __int_as_float(__builtin_amdgcn_mov_dpp(__float_as_int(m), 0x4E, 0xF, 0xF, true));
        int   oi = __builtin_amdgcn_mov_dpp(mi, 0x4E, 0xF, 0xF, true);
        if (om > m || (om == m && oi < mi)) { m = om; mi = oi; }
    }

    // flags: lane 0 holds d0 (MARK >=0.5), d1 (SHL >0.5), d2 (SHR >0.5)
    int flags = (v.x >= 0.5f ? 1 : 0) | (v.y > 0.5f ? 2 : 0) | (v.z > 0.5f ? 4 : 0);

    // 4 parallel depth-1 broadcasts: slices ALU_LO/ALU_HI/AX_CARRY live in
    // lane quads 1/2/3 of each 32-lane row group (slices 16-aligned -> mi&15)
    int flagsb = __shfl(flags, 0, 32);
    int d_lo   = __shfl(mi, 4, 32);
    int d_hi   = __shfl(mi, 8, 32);
    int d_sh   = __shfl(mi, 12, 32);

    int value = (d_lo & 15) | ((d_hi & 15) << 4);   // 0..255
    int shift = d_sh & 15;                           // <=15, min(.,31) no-op
    bool shl    = (flagsb & 2) != 0;
    bool active = (flagsb & 1) && (flagsb & 6);
    int result = shl ? ((value << shift) & 255) : (value >> shift);
    int t0 = 64 + (result & 15);
    int t1 = 80 + ((result >> 4) & 15);

    float add = active ? 2.0f : 0.0f;
    if (dbase     == t0 || dbase     == t1) v.x += add;
    if (dbase + 1 == t0 || dbase + 1 == t1) v.y += add;
    if (dbase + 2 == t0 || dbase + 2 == t1) v.z += add;
    if (dbase + 3 == t0 || dbase + 3 == t1) v.w += add;
    return v;
}

__global__ __launch_bounds__(256) void byteshift_kernel(const float* __restrict__ x,
                                                        float* __restrict__ out,
                                                        int half_rows) {
    int tid = blockIdx.x * blockDim.x + threadIdx.x;
    int lane_r = tid & 31;
    int g = tid >> 5;
    if (g >= half_rows) return;

    // two rows per thread, half_rows apart: both streams stay coalesced
    size_t off_a = (size_t)g * DD + lane_r * 4;
    size_t off_b = ((size_t)g + (size_t)half_rows) * DD + lane_r * 4;

    vf4 va = __builtin_nontemporal_load((const vf4*)(x + off_a));
    vf4 vb = __builtin_nontemporal_load((const vf4*)(x + off_b));

    vf4 oa = process_row(va, lane_r);
    vf4 ob = process_row(vb, lane_r);

    __builtin_nontemporal_store(oa, (vf4*)(out + off_a));
    __builtin_nontemporal_store(ob, (vf4*)(out + off_b));
}

extern "C" void kernel_launch(void* const* d_in, const int* in_sizes, int n_in,
                              void* d_out, int out_size, void* d_ws, size_t ws_size,
                              hipStream_t stream) {
    const float* x = (const float*)d_in[0];
    float* out = (float*)d_out;
    int n_rows = in_sizes[0] / DD;       // B*S = 262144 (even)
    int half_rows = n_rows / 2;
    int threads = 256;                    // 8 row-groups per block
    long long total = (long long)half_rows * 32;
    int blocks = (int)((total + threads - 1) / threads);
    hipLaunchKernelGGL(byteshift_kernel, dim3(blocks), dim3(threads), 0, stream,
                       x, out, half_rows);
}